// Round 1
// 131.087 us; speedup vs baseline: 1.2475x; 1.2475x over previous
//
#include <hip/hip_runtime.h>

static constexpr int B_ = 256;
static constexpr int R_ = 1152;
static constexpr int C_ = 10;
static constexpr int O_ = 16;
static constexpr int I_ = 8;
static constexpr int SCO = C_ * O_;   // 160
static constexpr int K_ = R_ * I_;    // 9216

typedef short bf16x8 __attribute__((ext_vector_type(8)));
typedef float f32x4  __attribute__((ext_vector_type(4)));

__device__ __forceinline__ unsigned short f2bf(float f) {
  union { float f; unsigned int u; } c; c.f = f;
  const unsigned int u = c.u;
  return (unsigned short)((u + 0x7fffu + ((u >> 16) & 1u)) >> 16);  // RNE
}
__device__ __forceinline__ float bf2f(unsigned short h) {
  union { unsigned int u; float f; } c; c.u = ((unsigned int)h) << 16; return c.f;
}

// ---------------------------------------------------------------------------
// prep0: grid 512.
//  - zero-init sbuf (3x160x256 partial accumulators), cnt (3x160), Z (it0=1152)
//  bx<256 : wraw[j] = bf16(W[j])  (native, coalesced). No scaled copy needed:
//           it0 softmax is uniform -> fold 1/1152 into k_gemm epilogue.
//  else   : single pass over x: stage fp32 to LDS; emit xb[b][k] bf16 directly
//           from the loaded values AND xT[k][b] bf16 via the LDS transpose.
// ---------------------------------------------------------------------------
__global__ __launch_bounds__(256) void prep0(const float* __restrict__ x,
                                             const float* __restrict__ W,
                                             unsigned short* __restrict__ xb,
                                             unsigned short* __restrict__ wraw,
                                             unsigned short* __restrict__ xT,
                                             float* __restrict__ sbuf,
                                             unsigned int* __restrict__ cnt,
                                             float* __restrict__ Z) {
  const int bx = blockIdx.x;
  const int t  = threadIdx.x;
  const int zi = bx * 256 + t;
  if (zi < 3 * 160 * 256) sbuf[zi] = 0.0f;
  if (zi < 512) cnt[zi] = 0u;
  if (zi < 32)  Z[zi] = (zi < 10) ? 1152.0f : 0.0f;
  if (bx < 256) {
    const float4* wf = (const float4*)W;
    ushort4* wr = (ushort4*)wraw;
    for (int idx = bx * 256 + t; idx < (R_ * C_ * O_ * I_) / 4; idx += 65536) {
      const float4 v4 = wf[idx];
      ushort4 r4;
      r4.x = f2bf(v4.x); r4.y = f2bf(v4.y); r4.z = f2bf(v4.z); r4.w = f2bf(v4.w);
      wr[idx] = r4;
    }
  } else {
    __shared__ float sx[18 * 8 * 68];
    const int idx2 = bx - 256;                 // 0..255
    const int bq = idx2 & 3, rseg = idx2 >> 2; // 64 segs x 18 r
    const int rbase = rseg * 18;
    for (int idx = t; idx < 64 * 36; idx += 256) {
      const int b = idx / 36, f4 = idx - b * 36;
      const size_t off = (size_t)(bq * 64 + b) * K_ + rbase * I_ + f4 * 4;
      const float4 val = *(const float4*)(x + off);
      ushort4 o4;
      o4.x = f2bf(val.x); o4.y = f2bf(val.y); o4.z = f2bf(val.z); o4.w = f2bf(val.w);
      *(ushort4*)(xb + off) = o4;
      const int rr = f4 >> 1, i4 = (f4 & 1) * 4;
      sx[(rr * 8 + i4 + 0) * 68 + b] = val.x;
      sx[(rr * 8 + i4 + 1) * 68 + b] = val.y;
      sx[(rr * 8 + i4 + 2) * 68 + b] = val.z;
      sx[(rr * 8 + i4 + 3) * 68 + b] = val.w;
    }
    __syncthreads();
    const int lane = t & 63, w = t >> 6;
    for (int row = w * 36; row < w * 36 + 36; ++row)
      xT[(size_t)(rbase * 8 + row) * 256 + bq * 64 + lane] = f2bf(sx[row * 68 + lane]);
  }
}

// ---------------------------------------------------------------------------
// k_gemm: split-K x2, grid 320 (2 blocks per (c,mtile) tile), 512 thr/block.
// wave w covers 576 k (72 r, 18 MFMAs). Block partial -> sred combine ->
// device-scope atomicAdd into sbuf[tile][256]; per-tile counter picks the
// last-arriving block, which atomic-reads the total (cross-XCD coherent),
// divides by Z[c] (=1152 at it0, sum-of-exp later), squashes, writes vb/out.
// XCD grouping: each XCD = 2 mtiles x all c x both subs -> 3.5 MB < 4 MB L2.
// ---------------------------------------------------------------------------
__global__ __launch_bounds__(512) void k_gemm(const unsigned short* __restrict__ xb,
                                              const unsigned short* __restrict__ Bm,
                                              const float* __restrict__ Zit,
                                              unsigned short* __restrict__ vb,
                                              float* __restrict__ out,
                                              float* __restrict__ sbuf,
                                              unsigned int* __restrict__ cnt,
                                              int final_) {
  __shared__ float sred[8][16 * 17];
  __shared__ int sflag;
  const int bx = blockIdx.x;
  const int g = (bx & 7) * 40 + (bx >> 3);      // 0..319
  const int mtile = g / 20;                      // 0..15
  const int rem = g - mtile * 20;
  const int c = rem >> 1, sub = rem & 1;
  const int t = threadIdx.x, lane = t & 63;
  const int w = __builtin_amdgcn_readfirstlane(t >> 6);  // 0..7
  const int mrow = lane & 15, quad = lane >> 4;
  const int m0 = mtile * 16;
  const int kb = sub * 4608 + w * 576;          // k-window base
  const int rb = sub * 576 + w * 72;            // r-window base

  const unsigned short* ap = xb + (size_t)(m0 + mrow) * K_ + kb + quad * 8;
  const unsigned short* bp = Bm + ((size_t)(rb + quad) * C_ + c) * 128 + mrow * 8;
  f32x4 acc = {0.0f, 0.0f, 0.0f, 0.0f};
#pragma unroll 6
  for (int kk = 0; kk < 18; ++kk) {
    const bf16x8 a = *(const bf16x8*)(ap + kk * 32);
    const bf16x8 b = *(const bf16x8*)(bp + (size_t)kk * 4 * C_ * 128);
    acc = __builtin_amdgcn_mfma_f32_16x16x32_bf16(a, b, acc, 0, 0, 0);
  }
#pragma unroll
  for (int rg = 0; rg < 4; ++rg)
    sred[w][mrow * 17 + quad * 4 + rg] = acc[rg];
  __syncthreads();
  const int tile = mtile * 10 + c;
  int m = 0, n = 0;
  if (t < 256) {
    if (final_) { m = t >> 4; n = t & 15; } else { n = t >> 4; m = t & 15; }
    const int e = n * 17 + m;
    const float val = ((sred[0][e] + sred[1][e]) + (sred[2][e] + sred[3][e]))
                    + ((sred[4][e] + sred[5][e]) + (sred[6][e] + sred[7][e]));
    atomicAdd(&sbuf[(size_t)tile * 256 + t], val);   // device-scope, cross-XCD safe
  }
  __syncthreads();                                    // drains the atomics (vmcnt 0)
  if (t == 0) sflag = (int)atomicAdd(&cnt[tile], 1u);
  __syncthreads();
  if (sflag == 0) return;                             // first finisher exits
  if (t < 256) {
    const float tot = atomicAdd(&sbuf[(size_t)tile * 256 + t], 0.0f);  // coherent read
    const float s = tot / Zit[c];
    const float v = s * fabsf(s) / (1.0f + s * s);    // squash (division-safe)
    if (final_) out[(size_t)(m0 + m) * SCO + c * 16 + n] = v;
    else        vb[(size_t)(c * 16 + n) * 256 + m0 + m] = f2bf(v);
  }
}

// ---------------------------------------------------------------------------
// k_pv: agreement + FUSED routing update, 8 r x 10 c per block (grid 144).
// Phase A: stage vb (80 KB) once into LDS, XOR-swizzled (b128 reads at the
//          optimal 8-pass instead of 16-way conflict); A-frags from xT.
// Phase B: P = xT^T . v via MFMA (80 MFMAs, B-frags from LDS).
// Phase C/D: P -> LDS (aliased over svb) in W-native order; contraction with
//          fp32 W, 32-lane shuffle reduce -> bsum[rl][c] in LDS.
// Phase E: bvec += bsum/256; e = exp(bvec) (|b|<<1, no max-sub needed);
//          per-block Z partial -> 10 atomicAdds. Softmax 1/Z deferred to
//          k_gemm epilogue (it is linear in s).
// Phase F: regen wb2[r,c,:] = bf16(wraw * e), vectorized ushort8.
// This eliminates the former k_bc kernel entirely.
// ---------------------------------------------------------------------------
__global__ __launch_bounds__(256) void k_pv(const unsigned short* __restrict__ xT,
                                            const unsigned short* __restrict__ vb,
                                            const float* __restrict__ W,
                                            const unsigned short* __restrict__ wraw,
                                            unsigned short* __restrict__ wb2,
                                            float* __restrict__ bvec,
                                            float* __restrict__ Zout,
                                            int first) {
  __shared__ __align__(16) unsigned short svb[40960];  // 80 KB; aliased as sp (40 KB)
  __shared__ float sbs[80];                            // bsum, then e
  const int bx = blockIdx.x;
  const int seg = (bx & 7) * 18 + (bx >> 3);    // 0..143, XCD-swizzled
  const int r0 = seg * 8;
  const int t = threadIdx.x, lane = t & 63;
  const int w = __builtin_amdgcn_readfirstlane(t >> 6);
  const int mrow = lane & 15, quad = lane >> 4;

  // A-frags from xT (global; issued early, consumed after the barrier)
  const unsigned short* ap = xT + (size_t)(seg * 64 + w * 16 + mrow) * 256 + quad * 8;
  bf16x8 afr[8];
#pragma unroll
  for (int kk = 0; kk < 8; ++kk) afr[kk] = *(const bf16x8*)(ap + kk * 32);

  // Phase A: stage vb -> LDS, swizzled. 5120 x 16B chunks, coalesced reads.
  {
    const char* src = (const char*)vb;
    char* dst = (char*)svb;
#pragma unroll
    for (int i = 0; i < 20; ++i) {
      const int ci = i * 256 + t;
      const int lin = ci * 16;
      const int n = ci >> 5;                    // 512 B per n-row
      *(bf16x8*)(dst + (lin ^ ((n & 7) << 4))) = *(const bf16x8*)(src + lin);
    }
  }
  __syncthreads();

  // Phase B: MFMAs from LDS
  f32x4 acc[10];
#pragma unroll
  for (int c = 0; c < 10; ++c) acc[c] = (f32x4){0.0f, 0.0f, 0.0f, 0.0f};
#pragma unroll
  for (int c = 0; c < 10; ++c) {
    const int n = c * 16 + mrow;
    const int base = n * 512 + quad * 16;
#pragma unroll
    for (int kk = 0; kk < 8; ++kk) {
      const bf16x8 b = *(const bf16x8*)((const char*)svb +
                        ((base + kk * 64) ^ ((n & 7) << 4)));
      acc[c] = __builtin_amdgcn_mfma_f32_16x16x32_bf16(afr[kk], b, acc[c], 0, 0, 0);
    }
  }
  __syncthreads();                              // all reads of svb done before overwrite

  // Phase C: P -> LDS (aliased), W-native (o*8+i) order
  float* sp = (float*)svb;
#pragma unroll
  for (int c = 0; c < 10; ++c)
#pragma unroll
    for (int rg = 0; rg < 4; ++rg) {
      const int ml = w * 16 + quad * 4 + rg;    // m = rl*8+i, col n=o=mrow
      sp[(c * 8 + (ml >> 3)) * 128 + mrow * 8 + (ml & 7)] = acc[c][rg];
    }
  __syncthreads();

  // Phase D: contraction with fp32 W, shuffle reduce
  const int p8 = t >> 5, l32 = t & 31;
#pragma unroll
  for (int ch = 0; ch < 10; ++ch) {
    const int pair = ch * 8 + p8;               // 0..79
    const int rl = pair / 10, c = pair - rl * 10;
    const float4 pv = *(const float4*)&sp[(c * 8 + rl) * 128 + l32 * 4];
    const float4 wv = *(const float4*)(W + (size_t)(r0 + rl) * 1280 + c * 128 + l32 * 4);
    float prod = wv.x * pv.x + wv.y * pv.y + wv.z * pv.z + wv.w * pv.w;
    prod += __shfl_xor(prod, 1);  prod += __shfl_xor(prod, 2);
    prod += __shfl_xor(prod, 4);  prod += __shfl_xor(prod, 8);
    prod += __shfl_xor(prod, 16);
    if (l32 == 0) sbs[rl * 10 + c] = prod;
  }
  __syncthreads();

  // Phase E: routing-logit update + exp (unnormalized softmax numerator)
  if (t < 80) {
    const int rl = t / 10, c = t - rl * 10;
    const int r = r0 + rl;
    float b = sbs[t] * (1.0f / 256.0f);
    if (!first) b += bvec[r * C_ + c];
    bvec[r * C_ + c] = b;
    sbs[t] = expf(b);                           // |b| << 1 here: overflow-safe
  }
  __syncthreads();
  if (t < 10) {
    float z = 0.0f;
#pragma unroll
    for (int rl = 0; rl < 8; ++rl) z += sbs[rl * 10 + t];
    atomicAdd(&Zout[t], z);
  }

  // Phase F: regen wb2 slice = bf16(wraw * e), 10240 elems, ushort8 vectorized
#pragma unroll
  for (int i = 0; i < 5; ++i) {
    const int base = i * 2048 + t * 8;
    const int rl = base / 1280, rem2 = base - rl * 1280;
    const int c = rem2 >> 7;
    const float e = sbs[rl * 10 + c];
    const size_t off = ((size_t)(r0 + rl) * C_ + c) * 128 + (rem2 & 127);
    const bf16x8 wv8 = *(const bf16x8*)(wraw + off);
    bf16x8 o8;
#pragma unroll
    for (int j = 0; j < 8; ++j)
      o8[j] = (short)f2bf(bf2f((unsigned short)wv8[j]) * e);
    *(bf16x8*)(wb2 + off) = o8;
  }
}

extern "C" void kernel_launch(void* const* d_in, const int* in_sizes, int n_in,
                              void* d_out, int out_size, void* d_ws, size_t ws_size,
                              hipStream_t stream) {
  const float* x = (const float*)d_in[0];  // (B,R,I) fp32
  const float* W = (const float*)d_in[1];  // (R,C,O,I) fp32
  float* out = (float*)d_out;              // (B,C,O,1) fp32

  float* bvec = (float*)d_ws;                              // R*C = 11520
  float* Z    = bvec + R_ * C_;                            // 32 (3 its x 10, padded)
  float* sbuf = Z + 32;                                    // 3 x 160 x 256
  unsigned int* cnt = (unsigned int*)(sbuf + 3 * 160 * 256);  // 512 (3 x 160 used)
  unsigned short* xb   = (unsigned short*)(cnt + 512);     // B*K
  unsigned short* wraw = xb + (size_t)B_ * K_;             // R*C*O*I
  unsigned short* xT   = wraw + (size_t)R_ * C_ * O_ * I_; // R*8*256
  unsigned short* vb   = xT + (size_t)R_ * 8 * 256;        // 160*256
  unsigned short* wb2  = vb + (size_t)160 * 256;           // R*C*O*I

  prep0<<<512, 256, 0, stream>>>(x, W, xb, wraw, xT, sbuf, cnt, Z);
  // it 0
  k_gemm<<<320, 512, 0, stream>>>(xb, wraw, Z + 0,  vb, out, sbuf + 0 * 40960, cnt + 0,   0);
  k_pv  <<<144, 256, 0, stream>>>(xT, vb, W, wraw, wb2, bvec, Z + 10, 1);
  // it 1
  k_gemm<<<320, 512, 0, stream>>>(xb, wb2,  Z + 10, vb, out, sbuf + 1 * 40960, cnt + 160, 0);
  k_pv  <<<144, 256, 0, stream>>>(xT, vb, W, wraw, wb2, bvec, Z + 20, 0);
  // it 2 (final)
  k_gemm<<<320, 512, 0, stream>>>(xb, wb2,  Z + 20, vb, out, sbuf + 2 * 40960, cnt + 320, 1);
}